// Round 6
// baseline (147.744 us; speedup 1.0000x reference)
//
#include <hip/hip_runtime.h>

// ScaledDotProductAttention: B=4,H=8,S=2048,Dh=64, fp32 in/out, key-padding mask.
// Flash-style, bf16 MFMA 16x16x32, fp32 accum, no max-tracking (scores bounded,
// softmax shift-invariant) -> key-split partials are ADDITIVE:
//   kernel1: grid (32 qblk, 32 bh, NS splits), each split writes unnormalized
//            partial O (f16) + partial rowsum (f32) to d_ws.
//   kernel2: sums active splits (from lens) + normalizes -> d_out. Deterministic.
// NS chosen by ws_size (4 -> 2 -> 1-direct). Batch-interleaved blockIdx.y.

#define S_LEN 2048
#define DH 64
// (1/sqrt(512)) * log2(e): scores computed directly in log2 domain
#define QK_SCALE ((float)(1.4426950408889634 / 22.627416997969522))

typedef __attribute__((ext_vector_type(8))) short bf16x8;
typedef __attribute__((ext_vector_type(4))) float f32x4;

__device__ __forceinline__ short f2bf(float f) {
    __bf16 h = (__bf16)f;               // hardware RNE convert on gfx950
    return __builtin_bit_cast(short, h);
}
__device__ __forceinline__ short f2h(float f) {
    _Float16 h = (_Float16)f;
    return __builtin_bit_cast(short, h);
}
__device__ __forceinline__ float h2f(short s) {
    return (float)__builtin_bit_cast(_Float16, s);
}

// XOR swizzle: 16B blocks within a 128B row, keyed by row&7 (G4 fix)
#define SW(r, e) ((e) ^ (((r) & 7) << 3))

__global__ __launch_bounds__(256, 2)
void attn_fwd(const float* __restrict__ Qg, const float* __restrict__ Kg,
              const float* __restrict__ Vg, const int* __restrict__ lens,
              float* __restrict__ Og, short* __restrict__ pW,
              float* __restrict__ dW, int NS, int CH)
{
    __shared__ short Klds[2][64][64];  // K tile [key][d], swizzled, double-buffered
    __shared__ short Vt[2][64][64];    // V^T tile [d][key], swizzled, double-buffered
    __shared__ short Plds[4][16][64];  // per-wave P [q][key], swizzled

    const int tid  = threadIdx.x;
    const int wave = tid >> 6;
    const int lane = tid & 63;
    const int lr   = lane & 15;
    const int lg   = lane >> 4;

    // batch-interleave: consecutive y cycle through batches (long batches start early)
    const int bh = ((blockIdx.y & 3) << 3) | (blockIdx.y >> 2);
    const int L  = lens[bh >> 3];              // H = 8
    const int start = blockIdx.z * CH;
    if (start >= L) return;                    // empty split: reduce skips via lens
    const int end = min(start + CH, L);
    const int ntiles = (end - start + 63) >> 6;

    const int q0 = blockIdx.x * 64 + wave * 16;
    const size_t base = (size_t)bh * S_LEN * DH;

    // ---- Q fragments (A-layout: row = lane%16, k = 8*(lane/16)+j), log2-scaled ----
    bf16x8 qf[2];
    {
        const float* qrow = Qg + base + (size_t)(q0 + lr) * DH + 8 * lg;
        #pragma unroll
        for (int ks = 0; ks < 2; ++ks) {
            float4 a = *(const float4*)(qrow + 32 * ks);
            float4 b = *(const float4*)(qrow + 32 * ks + 4);
            bf16x8 f;
            f[0] = f2bf(a.x * QK_SCALE); f[1] = f2bf(a.y * QK_SCALE);
            f[2] = f2bf(a.z * QK_SCALE); f[3] = f2bf(a.w * QK_SCALE);
            f[4] = f2bf(b.x * QK_SCALE); f[5] = f2bf(b.y * QK_SCALE);
            f[6] = f2bf(b.z * QK_SCALE); f[7] = f2bf(b.w * QK_SCALE);
            qf[ks] = f;
        }
    }

    f32x4 Of[4];
    #pragma unroll
    for (int n = 0; n < 4; ++n) Of[n] = (f32x4){0.f, 0.f, 0.f, 0.f};
    f32x4 Dsum = (f32x4){0.f, 0.f, 0.f, 0.f};
    bf16x8 ones;
    #pragma unroll
    for (int j = 0; j < 8; ++j) ones[j] = (short)0x3F80;   // bf16 1.0

    const int krow = tid >> 4;          // staging row 0..15 (+16*it)
    const int kc4  = tid & 15;

    float4 kreg[4];
    float  vreg[16];

    // ---- prefetch tile 0 into registers ----
    {
        const float4* kt = (const float4*)(Kg + base + (size_t)start * DH);
        #pragma unroll
        for (int it = 0; it < 4; ++it) kreg[it] = kt[(krow + 16 * it) * 16 + kc4];
        const float* vt = Vg + base + (size_t)start * DH;
        #pragma unroll
        for (int i = 0; i < 16; ++i) {
            int key = wave * 16 + ((i + (lane >> 3)) & 15);
            vreg[i] = vt[key * DH + lane];
        }
    }
    // ---- write tile 0 to buf 0 ----
    {
        #pragma unroll
        for (int it = 0; it < 4; ++it) {
            int row = krow + 16 * it;
            short4 s;
            s.x = f2bf(kreg[it].x); s.y = f2bf(kreg[it].y);
            s.z = f2bf(kreg[it].z); s.w = f2bf(kreg[it].w);
            *(short4*)&Klds[0][row][SW(row, kc4 * 4)] = s;
        }
        #pragma unroll
        for (int i = 0; i < 16; ++i) {
            int key = wave * 16 + ((i + (lane >> 3)) & 15);
            Vt[0][lane][SW(lane, key)] = f2bf(vreg[i]);
        }
    }
    __syncthreads();

    for (int t = 0; t < ntiles; ++t) {
        const int cur = t & 1;
        const int kb = start + t * 64;
        const bool pre = (t + 1 < ntiles);

        // ---- issue next tile's global loads early (latency hides under compute) ----
        if (pre) {
            const float4* kt = (const float4*)(Kg + base + (size_t)(kb + 64) * DH);
            #pragma unroll
            for (int it = 0; it < 4; ++it) kreg[it] = kt[(krow + 16 * it) * 16 + kc4];
            const float* vt = Vg + base + (size_t)(kb + 64) * DH;
            #pragma unroll
            for (int i = 0; i < 16; ++i) {
                int key = wave * 16 + ((i + (lane >> 3)) & 15);
                vreg[i] = vt[key * DH + lane];
            }
        }

        // ---- S = (Q*scale*log2e) K^T ----
        f32x4 Sv[4];
        #pragma unroll
        for (int n = 0; n < 4; ++n) Sv[n] = (f32x4){0.f, 0.f, 0.f, 0.f};
        #pragma unroll
        for (int ks = 0; ks < 2; ++ks) {
            #pragma unroll
            for (int n = 0; n < 4; ++n) {
                bf16x8 kf = *(const bf16x8*)&Klds[cur][16 * n + lr][SW(16 * n + lr, 8 * lg + 32 * ks)];
                Sv[n] = __builtin_amdgcn_mfma_f32_16x16x32_bf16(qf[ks], kf, Sv[n], 0, 0, 0);
            }
        }

        // ---- boundary mask (key col = 16n + lane%16); only fires when end == L ----
        if (kb + 64 > L) {
            #pragma unroll
            for (int n = 0; n < 4; ++n)
                if (kb + 16 * n + lr >= L) {
                    Sv[n][0] = -1e30f; Sv[n][1] = -1e30f;
                    Sv[n][2] = -1e30f; Sv[n][3] = -1e30f;
                }
        }

        // ---- P = exp2(S) -> per-wave LDS (D-layout scatter) ----
        #pragma unroll
        for (int r = 0; r < 4; ++r) {
            int q = 4 * lg + r;
            #pragma unroll
            for (int n = 0; n < 4; ++n)
                Plds[wave][q][SW(q, 16 * n + lr)] = f2bf(exp2f(Sv[n][r]));
        }

        // ---- O += P V ; Dsum += P * ones (row sums via MFMA) ----
        #pragma unroll
        for (int ks = 0; ks < 2; ++ks) {
            bf16x8 pf = *(const bf16x8*)&Plds[wave][lr][SW(lr, 8 * lg + 32 * ks)];
            Dsum = __builtin_amdgcn_mfma_f32_16x16x32_bf16(pf, ones, Dsum, 0, 0, 0);
            #pragma unroll
            for (int n = 0; n < 4; ++n) {
                bf16x8 vf = *(const bf16x8*)&Vt[cur][16 * n + lr][SW(16 * n + lr, 8 * lg + 32 * ks)];
                Of[n] = __builtin_amdgcn_mfma_f32_16x16x32_bf16(pf, vf, Of[n], 0, 0, 0);
            }
        }

        // ---- convert + write next tile into the other buffer ----
        if (pre) {
            const int b = cur ^ 1;
            #pragma unroll
            for (int it = 0; it < 4; ++it) {
                int row = krow + 16 * it;
                short4 s;
                s.x = f2bf(kreg[it].x); s.y = f2bf(kreg[it].y);
                s.z = f2bf(kreg[it].z); s.w = f2bf(kreg[it].w);
                *(short4*)&Klds[b][row][SW(row, kc4 * 4)] = s;
            }
            #pragma unroll
            for (int i = 0; i < 16; ++i) {
                int key = wave * 16 + ((i + (lane >> 3)) & 15);
                Vt[b][lane][SW(lane, key)] = f2bf(vreg[i]);
            }
        }
        __syncthreads();
    }

    // ---- epilogue ----
    if (NS == 1) {
        float inv[4];
        #pragma unroll
        for (int r = 0; r < 4; ++r) inv[r] = 1.f / Dsum[r];
        float* orow = Og + base + (size_t)q0 * DH;
        #pragma unroll
        for (int r = 0; r < 4; ++r) {
            int q = 4 * lg + r;
            #pragma unroll
            for (int n = 0; n < 4; ++n)
                orow[(size_t)q * DH + 16 * n + lr] = Of[n][r] * inv[r];
        }
    } else {
        // partial O (f16, unnormalized) + partial denom (f32)
        short* prow = pW + ((size_t)(blockIdx.z * 32 + bh) * S_LEN + q0) * DH;
        #pragma unroll
        for (int r = 0; r < 4; ++r) {
            int q = 4 * lg + r;
            #pragma unroll
            for (int n = 0; n < 4; ++n)
                prow[(size_t)q * DH + 16 * n + lr] = f2h(Of[n][r]);
        }
        if (lr == 0) {
            #pragma unroll
            for (int r = 0; r < 4; ++r)
                dW[(size_t)(blockIdx.z * 32 + bh) * S_LEN + q0 + 4 * lg + r] = Dsum[r];
        }
    }
}

__global__ __launch_bounds__(256)
void attn_reduce(const int* __restrict__ lens, const short* __restrict__ pW,
                 const float* __restrict__ dW, float* __restrict__ Og,
                 int NS, int CH)
{
    const size_t i = ((size_t)blockIdx.x * 256 + threadIdx.x) * 4;  // 4 floats/thread
    const int bh = (int)(i >> 17);                 // 2048*64 = 2^17 per bh
    const int q  = (int)((i >> 6) & (S_LEN - 1));
    const int L  = lens[bh >> 3];
    const int nact = min(NS, (L + CH - 1) / CH);

    float ax = 0.f, ay = 0.f, az = 0.f, aw = 0.f, den = 0.f;
    for (int s = 0; s < nact; ++s) {
        const size_t sb = (size_t)(s * 32 + bh);
        short4 h = *(const short4*)(pW + sb * (S_LEN * DH) + (i & (S_LEN * DH - 1)));
        ax += h2f(h.x); ay += h2f(h.y); az += h2f(h.z); aw += h2f(h.w);
        den += dW[sb * S_LEN + q];
    }
    const float inv = 1.f / den;
    float4 o; o.x = ax * inv; o.y = ay * inv; o.z = az * inv; o.w = aw * inv;
    *(float4*)(Og + i) = o;
}

extern "C" void kernel_launch(void* const* d_in, const int* in_sizes, int n_in,
                              void* d_out, int out_size, void* d_ws, size_t ws_size,
                              hipStream_t stream) {
    const float* Q = (const float*)d_in[0];
    const float* K = (const float*)d_in[1];
    const float* V = (const float*)d_in[2];
    const int* lens = (const int*)d_in[3];
    float* O = (float*)d_out;

    const size_t outN = (size_t)4 * 8 * S_LEN * DH;            // 4,194,304
    auto need = [&](int ns) {
        return (size_t)ns * (outN * 2 + (size_t)32 * S_LEN * 4);
    };
    int NS = (ws_size >= need(4)) ? 4 : (ws_size >= need(2)) ? 2 : 1;
    const int CH = S_LEN / NS;

    short* pW = (short*)d_ws;
    float* dW = (float*)((char*)d_ws + (size_t)NS * outN * 2);

    dim3 grid1(S_LEN / 64, 4 * 8, NS);
    attn_fwd<<<grid1, 256, 0, stream>>>(Q, K, V, lens, O, pW, dW, NS, CH);
    if (NS > 1) {
        attn_reduce<<<(unsigned)(outN / 1024), 256, 0, stream>>>(lens, pW, dW, O, NS, CH);
    }
}

// Round 8
// 139.059 us; speedup vs baseline: 1.0625x; 1.0625x over previous
//
#include <hip/hip_runtime.h>

// ScaledDotProductAttention: B=4,H=8,S=2048,Dh=64, fp32 in/out, key-padding mask.
// Flash-style, bf16 MFMA 16x16x32, fp32 accum, no max-tracking (scores bounded,
// softmax shift-invariant). SWAPPED QK^T: S^T = mfma(K, Q) so each lane owns one
// q-column of P -> P write = 4x ds_write_b64, PV A-frag = ds_read_b128 (DS ops
// per tile 54 -> 26; r6 showed DS pipe ~66% busy was the limiter).
// Double-buffered K/V LDS, reg-prefetch staging. NS-split reverted (r6: neutral).

#define S_LEN 2048
#define DH 64
// (1/sqrt(512)) * log2(e): scores computed directly in log2 domain
#define QK_SCALE ((float)(1.4426950408889634 / 22.627416997969522))

typedef __attribute__((ext_vector_type(8))) short bf16x8;
typedef __attribute__((ext_vector_type(4))) float f32x4;

__device__ __forceinline__ short f2bf(float f) {
    __bf16 h = (__bf16)f;               // hardware RNE convert on gfx950
    return __builtin_bit_cast(short, h);
}

// XOR swizzle: 16B (8-elem) blocks within a 128B row, keyed by row&7 (G4 fix)
#define SW(r, e) ((e) ^ (((r) & 7) << 3))

__global__ __launch_bounds__(256, 2)
void attn_fwd(const float* __restrict__ Qg, const float* __restrict__ Kg,
              const float* __restrict__ Vg, const int* __restrict__ lens,
              float* __restrict__ Og)
{
    __shared__ short Klds[2][64][64];  // K tile [key][d], swizzled, double-buffered
    __shared__ short Vt[2][64][64];    // V^T tile [d][key], swizzled, double-buffered
    __shared__ short Plds[4][16][64];  // per-wave P [q][key], swizzled

    const int tid  = threadIdx.x;
    const int wave = tid >> 6;
    const int lane = tid & 63;
    const int lr   = lane & 15;
    const int lg   = lane >> 4;

    // batch-interleave across blockIdx.y (long batches start early)
    const int bh = ((blockIdx.y & 3) << 3) | (blockIdx.y >> 2);
    const int L  = lens[bh >> 3];              // H = 8
    const int q0 = blockIdx.x * 64 + wave * 16;
    const size_t base = (size_t)bh * S_LEN * DH;

    // ---- Q fragments (B-operand: col=q=lane%16, k=d=8*lg+j+32ks), log2-scaled ----
    bf16x8 qf[2];
    {
        const float* qrow = Qg + base + (size_t)(q0 + lr) * DH + 8 * lg;
        #pragma unroll
        for (int ks = 0; ks < 2; ++ks) {
            float4 a = *(const float4*)(qrow + 32 * ks);
            float4 b = *(const float4*)(qrow + 32 * ks + 4);
            bf16x8 f;
            f[0] = f2bf(a.x * QK_SCALE); f[1] = f2bf(a.y * QK_SCALE);
            f[2] = f2bf(a.z * QK_SCALE); f[3] = f2bf(a.w * QK_SCALE);
            f[4] = f2bf(b.x * QK_SCALE); f[5] = f2bf(b.y * QK_SCALE);
            f[6] = f2bf(b.z * QK_SCALE); f[7] = f2bf(b.w * QK_SCALE);
            qf[ks] = f;
        }
    }

    f32x4 Of[4];
    #pragma unroll
    for (int n = 0; n < 4; ++n) Of[n] = (f32x4){0.f, 0.f, 0.f, 0.f};
    f32x4 Dsum = (f32x4){0.f, 0.f, 0.f, 0.f};
    bf16x8 ones;
    #pragma unroll
    for (int j = 0; j < 8; ++j) ones[j] = (short)0x3F80;   // bf16 1.0

    const int ntiles = (L + 63) >> 6;   // skip fully-masked key tiles (exact)

    // K staging decomposition: row = tid>>3 (+32), c8 = (tid&7)*8
    const int krow = tid >> 3;
    const int kc8  = (tid & 7) * 8;

    float4 kreg[4];     // 2 rows x 2 float4
    float  vreg[16];    // column d=lane, keys wave*16..+15

    // ---- prefetch tile 0 into registers ----
    {
        const float* kt = Kg + base;
        #pragma unroll
        for (int p = 0; p < 2; ++p) {
            kreg[2 * p]     = *(const float4*)(kt + (krow + 32 * p) * DH + kc8);
            kreg[2 * p + 1] = *(const float4*)(kt + (krow + 32 * p) * DH + kc8 + 4);
        }
        const float* vt = Vg + base;
        #pragma unroll
        for (int i = 0; i < 16; ++i)
            vreg[i] = vt[(wave * 16 + i) * DH + lane];
    }
    // ---- write tile 0 to buf 0 ----
    {
        #pragma unroll
        for (int p = 0; p < 2; ++p) {
            int row = krow + 32 * p;
            bf16x8 s;
            s[0] = f2bf(kreg[2*p].x); s[1] = f2bf(kreg[2*p].y);
            s[2] = f2bf(kreg[2*p].z); s[3] = f2bf(kreg[2*p].w);
            s[4] = f2bf(kreg[2*p+1].x); s[5] = f2bf(kreg[2*p+1].y);
            s[6] = f2bf(kreg[2*p+1].z); s[7] = f2bf(kreg[2*p+1].w);
            *(bf16x8*)&Klds[0][row][SW(row, kc8)] = s;
        }
        bf16x8 a, b;
        #pragma unroll
        for (int i = 0; i < 8; ++i) { a[i] = f2bf(vreg[i]); b[i] = f2bf(vreg[8 + i]); }
        *(bf16x8*)&Vt[0][lane][SW(lane, wave * 16)]     = a;
        *(bf16x8*)&Vt[0][lane][SW(lane, wave * 16 + 8)] = b;
    }
    __syncthreads();

    for (int t = 0; t < ntiles; ++t) {
        const int cur = t & 1;
        const int kb = t * 64;
        const bool pre = (t + 1 < ntiles);

        // ---- issue next tile's global loads early (latency hides under compute) ----
        if (pre) {
            const float* kt = Kg + base + (size_t)(kb + 64) * DH;
            #pragma unroll
            for (int p = 0; p < 2; ++p) {
                kreg[2 * p]     = *(const float4*)(kt + (krow + 32 * p) * DH + kc8);
                kreg[2 * p + 1] = *(const float4*)(kt + (krow + 32 * p) * DH + kc8 + 4);
            }
            const float* vt = Vg + base + (size_t)(kb + 64) * DH;
            #pragma unroll
            for (int i = 0; i < 16; ++i)
                vreg[i] = vt[(wave * 16 + i) * DH + lane];
        }

        // ---- S^T = mfma(K, Q): Sv[n][r] = S[q=q0+lr][key = kb+16n+4*lg+r] ----
        f32x4 Sv[4];
        #pragma unroll
        for (int n = 0; n < 4; ++n) Sv[n] = (f32x4){0.f, 0.f, 0.f, 0.f};
        #pragma unroll
        for (int ks = 0; ks < 2; ++ks) {
            #pragma unroll
            for (int n = 0; n < 4; ++n) {
                bf16x8 kf = *(const bf16x8*)&Klds[cur][16 * n + lr][SW(16 * n + lr, 8 * lg + 32 * ks)];
                Sv[n] = __builtin_amdgcn_mfma_f32_16x16x32_bf16(kf, qf[ks], Sv[n], 0, 0, 0);
            }
        }

        // ---- boundary mask: key = kb + 16n + 4*lg + r ----
        if (kb + 64 > L) {
            #pragma unroll
            for (int n = 0; n < 4; ++n) {
                const int kbase = kb + 16 * n + 4 * lg;
                #pragma unroll
                for (int r = 0; r < 4; ++r)
                    if (kbase + r >= L) Sv[n][r] = -1e30f;
            }
        }

        // ---- P = exp2(S): lane-local row-chunk write, 4x ds_write_b64 ----
        #pragma unroll
        for (int n = 0; n < 4; ++n) {
            short4 pq;
            pq.x = f2bf(exp2f(Sv[n][0]));
            pq.y = f2bf(exp2f(Sv[n][1]));
            pq.z = f2bf(exp2f(Sv[n][2]));
            pq.w = f2bf(exp2f(Sv[n][3]));
            *(short4*)&Plds[wave][lr][SW(lr, 16 * n + 4 * lg)] = pq;
        }

        // ---- O += P V ; Dsum += P * ones (row sums via MFMA) ----
        #pragma unroll
        for (int ks = 0; ks < 2; ++ks) {
            bf16x8 pf = *(const bf16x8*)&Plds[wave][lr][SW(lr, 8 * lg + 32 * ks)];
            Dsum = __builtin_amdgcn_mfma_f32_16x16x32_bf16(pf, ones, Dsum, 0, 0, 0);
            #pragma unroll
            for (int n = 0; n < 4; ++n) {
                bf16x8 vf = *(const bf16x8*)&Vt[cur][16 * n + lr][SW(16 * n + lr, 8 * lg + 32 * ks)];
                Of[n] = __builtin_amdgcn_mfma_f32_16x16x32_bf16(pf, vf, Of[n], 0, 0, 0);
            }
        }

        // ---- convert + write next tile into the other buffer ----
        if (pre) {
            const int b = cur ^ 1;
            #pragma unroll
            for (int p = 0; p < 2; ++p) {
                int row = krow + 32 * p;
                bf16x8 s;
                s[0] = f2bf(kreg[2*p].x); s[1] = f2bf(kreg[2*p].y);
                s[2] = f2bf(kreg[2*p].z); s[3] = f2bf(kreg[2*p].w);
                s[4] = f2bf(kreg[2*p+1].x); s[5] = f2bf(kreg[2*p+1].y);
                s[6] = f2bf(kreg[2*p+1].z); s[7] = f2bf(kreg[2*p+1].w);
                *(bf16x8*)&Klds[b][row][SW(row, kc8)] = s;
            }
            bf16x8 a, bb;
            #pragma unroll
            for (int i = 0; i < 8; ++i) { a[i] = f2bf(vreg[i]); bb[i] = f2bf(vreg[8 + i]); }
            *(bf16x8*)&Vt[b][lane][SW(lane, wave * 16)]     = a;
            *(bf16x8*)&Vt[b][lane][SW(lane, wave * 16 + 8)] = bb;
        }
        __syncthreads();
    }

    // ---- epilogue: O / rowsum -> global (q = 4*lg+r, d = 16n+lr) ----
    float inv[4];
    #pragma unroll
    for (int r = 0; r < 4; ++r) inv[r] = 1.f / Dsum[r];
    float* orow = Og + base + (size_t)q0 * DH;
    #pragma unroll
    for (int r = 0; r < 4; ++r) {
        int q = 4 * lg + r;
        #pragma unroll
        for (int n = 0; n < 4; ++n)
            orow[(size_t)q * DH + 16 * n + lr] = Of[n][r] * inv[r];
    }
}

extern "C" void kernel_launch(void* const* d_in, const int* in_sizes, int n_in,
                              void* d_out, int out_size, void* d_ws, size_t ws_size,
                              hipStream_t stream) {
    const float* Q = (const float*)d_in[0];
    const float* K = (const float*)d_in[1];
    const float* V = (const float*)d_in[2];
    const int* lens = (const int*)d_in[3];
    float* O = (float*)d_out;
    dim3 grid(S_LEN / 64, 4 * 8);
    attn_fwd<<<grid, 256, 0, stream>>>(Q, K, V, lens, O);
}

// Round 9
// 137.012 us; speedup vs baseline: 1.0783x; 1.0149x over previous
//
#include <hip/hip_runtime.h>

// ScaledDotProductAttention: B=4,H=8,S=2048,Dh=64, fp32 in/out, key-padding mask.
// Flash-style, bf16 MFMA 16x16x32, fp32 accum, no max-tracking (scores bounded,
// softmax shift-invariant). Swapped QK^T (S^T = mfma(K,Q)) + KEY-PERMUTED V:
// PV contracts over keys, so P and V share a consistent key-permutation pi();
// chosen so each lane's QK output registers ARE its PV A-fragment -> P never
// touches LDS (r8's mid-tile P write->lgkmcnt->read chain removed). V staged
// row-permuted, still 2x ds_write_b128. LDS 40->32KB.

#define S_LEN 2048
#define DH 64
// (1/sqrt(512)) * log2(e): scores computed directly in log2 domain
#define QK_SCALE ((float)(1.4426950408889634 / 22.627416997969522))

typedef __attribute__((ext_vector_type(8))) short bf16x8;
typedef __attribute__((ext_vector_type(4))) float f32x4;

__device__ __forceinline__ short f2bf(float f) {
    __bf16 h = (__bf16)f;               // hardware RNE convert on gfx950
    return __builtin_bit_cast(short, h);
}

// XOR swizzle: 16B (8-elem) blocks within a 128B row, keyed by row&7 (G4 fix)
#define SW(r, e) ((e) ^ (((r) & 7) << 3))

__global__ __launch_bounds__(256, 2)
void attn_fwd(const float* __restrict__ Qg, const float* __restrict__ Kg,
              const float* __restrict__ Vg, const int* __restrict__ lens,
              float* __restrict__ Og)
{
    __shared__ short Klds[2][64][64];  // K tile [key][d], swizzled, double-buffered
    __shared__ short Vt[2][64][64];    // V^T tile [d][slot], slot=pi^-1(key), swizzled

    const int tid  = threadIdx.x;
    const int wave = tid >> 6;
    const int lane = tid & 63;
    const int lr   = lane & 15;
    const int lg   = lane >> 4;

    // batch-interleave across blockIdx.y (long batches start early)
    const int bh = ((blockIdx.y & 3) << 3) | (blockIdx.y >> 2);
    const int L  = lens[bh >> 3];              // H = 8
    const int q0 = blockIdx.x * 64 + wave * 16;
    const size_t base = (size_t)bh * S_LEN * DH;

    // ---- Q fragments (B-operand: col=q=lane%16, k=d=8*lg+j+32ks), log2-scaled ----
    bf16x8 qf[2];
    {
        const float* qrow = Qg + base + (size_t)(q0 + lr) * DH + 8 * lg;
        #pragma unroll
        for (int ks = 0; ks < 2; ++ks) {
            float4 a = *(const float4*)(qrow + 32 * ks);
            float4 b = *(const float4*)(qrow + 32 * ks + 4);
            bf16x8 f;
            f[0] = f2bf(a.x * QK_SCALE); f[1] = f2bf(a.y * QK_SCALE);
            f[2] = f2bf(a.z * QK_SCALE); f[3] = f2bf(a.w * QK_SCALE);
            f[4] = f2bf(b.x * QK_SCALE); f[5] = f2bf(b.y * QK_SCALE);
            f[6] = f2bf(b.z * QK_SCALE); f[7] = f2bf(b.w * QK_SCALE);
            qf[ks] = f;
        }
    }

    f32x4 Of[4];
    #pragma unroll
    for (int n = 0; n < 4; ++n) Of[n] = (f32x4){0.f, 0.f, 0.f, 0.f};
    f32x4 Dsum = (f32x4){0.f, 0.f, 0.f, 0.f};
    bf16x8 ones;
    #pragma unroll
    for (int j = 0; j < 8; ++j) ones[j] = (short)0x3F80;   // bf16 1.0

    const int ntiles = (L + 63) >> 6;   // skip fully-masked key tiles (exact)

    // K staging decomposition: row = tid>>3 (+32), c8 = (tid&7)*8
    const int krow = tid >> 3;
    const int kc8  = (tid & 7) * 8;

    // V staging: wave w stages SLOTS 16w..16w+15; slot 16w+i holds key pi(16w+i):
    //   key(i) = 16*(w&~1) + 16*((i>>2)&1) + 8*(w&1) + 4*(i>>3) + (i&3)
    int vkey[16];
    #pragma unroll
    for (int i = 0; i < 16; ++i)
        vkey[i] = 16 * (wave & ~1) + (((i >> 2) & 1) << 4) + ((wave & 1) << 3)
                + ((i >> 3) << 2) + (i & 3);

    float4 kreg[4];     // 2 rows x 2 float4
    float  vreg[16];    // column d=lane, permuted keys

    // ---- prefetch tile 0 into registers ----
    {
        const float* kt = Kg + base;
        #pragma unroll
        for (int p = 0; p < 2; ++p) {
            kreg[2 * p]     = *(const float4*)(kt + (krow + 32 * p) * DH + kc8);
            kreg[2 * p + 1] = *(const float4*)(kt + (krow + 32 * p) * DH + kc8 + 4);
        }
        const float* vt = Vg + base;
        #pragma unroll
        for (int i = 0; i < 16; ++i)
            vreg[i] = vt[vkey[i] * DH + lane];
    }
    // ---- write tile 0 to buf 0 ----
    {
        #pragma unroll
        for (int p = 0; p < 2; ++p) {
            int row = krow + 32 * p;
            bf16x8 s;
            s[0] = f2bf(kreg[2*p].x); s[1] = f2bf(kreg[2*p].y);
            s[2] = f2bf(kreg[2*p].z); s[3] = f2bf(kreg[2*p].w);
            s[4] = f2bf(kreg[2*p+1].x); s[5] = f2bf(kreg[2*p+1].y);
            s[6] = f2bf(kreg[2*p+1].z); s[7] = f2bf(kreg[2*p+1].w);
            *(bf16x8*)&Klds[0][row][SW(row, kc8)] = s;
        }
        bf16x8 a, b;
        #pragma unroll
        for (int i = 0; i < 8; ++i) { a[i] = f2bf(vreg[i]); b[i] = f2bf(vreg[8 + i]); }
        *(bf16x8*)&Vt[0][lane][SW(lane, wave * 16)]     = a;
        *(bf16x8*)&Vt[0][lane][SW(lane, wave * 16 + 8)] = b;
    }
    __syncthreads();

    for (int t = 0; t < ntiles; ++t) {
        const int cur = t & 1;
        const int kb = t * 64;
        const bool pre = (t + 1 < ntiles);

        // ---- issue next tile's global loads early (latency hides under compute) ----
        if (pre) {
            const float* kt = Kg + base + (size_t)(kb + 64) * DH;
            #pragma unroll
            for (int p = 0; p < 2; ++p) {
                kreg[2 * p]     = *(const float4*)(kt + (krow + 32 * p) * DH + kc8);
                kreg[2 * p + 1] = *(const float4*)(kt + (krow + 32 * p) * DH + kc8 + 4);
            }
            const float* vt = Vg + base + (size_t)(kb + 64) * DH;
            #pragma unroll
            for (int i = 0; i < 16; ++i)
                vreg[i] = vt[vkey[i] * DH + lane];
        }

        // ---- S^T = mfma(K, Q): Sv[n][r] = S[q=q0+lr][key = kb+16n+4*lg+r] ----
        f32x4 Sv[4];
        #pragma unroll
        for (int n = 0; n < 4; ++n) Sv[n] = (f32x4){0.f, 0.f, 0.f, 0.f};
        #pragma unroll
        for (int ks = 0; ks < 2; ++ks) {
            #pragma unroll
            for (int n = 0; n < 4; ++n) {
                bf16x8 kf = *(const bf16x8*)&Klds[cur][16 * n + lr][SW(16 * n + lr, 8 * lg + 32 * ks)];
                Sv[n] = __builtin_amdgcn_mfma_f32_16x16x32_bf16(kf, qf[ks], Sv[n], 0, 0, 0);
            }
        }

        // ---- boundary mask: key = kb + 16n + 4*lg + r ----
        if (kb + 64 > L) {
            #pragma unroll
            for (int n = 0; n < 4; ++n) {
                const int kbase = kb + 16 * n + 4 * lg;
                #pragma unroll
                for (int r = 0; r < 4; ++r)
                    if (kbase + r >= L) Sv[n][r] = -1e30f;
            }
        }

        // ---- P = exp2(S) directly into PV A-fragments (slot s=8lg+j+32ks holds
        //      key 16*(2ks+(j>>2)) + 4lg + (j&3) = Sv[2ks+(j>>2)][j&3]) ----
        bf16x8 pf[2];
        #pragma unroll
        for (int ks = 0; ks < 2; ++ks) {
            #pragma unroll
            for (int h = 0; h < 2; ++h) {
                #pragma unroll
                for (int r = 0; r < 4; ++r)
                    pf[ks][4 * h + r] = f2bf(exp2f(Sv[2 * ks + h][r]));
            }
        }

        // ---- O += P' V' ; Dsum += P' * ones (permutation-invariant) ----
        #pragma unroll
        for (int ks = 0; ks < 2; ++ks) {
            Dsum = __builtin_amdgcn_mfma_f32_16x16x32_bf16(pf[ks], ones, Dsum, 0, 0, 0);
            #pragma unroll
            for (int n = 0; n < 4; ++n) {
                bf16x8 vf = *(const bf16x8*)&Vt[cur][16 * n + lr][SW(16 * n + lr, 8 * lg + 32 * ks)];
                Of[n] = __builtin_amdgcn_mfma_f32_16x16x32_bf16(pf[ks], vf, Of[n], 0, 0, 0);
            }
        }

        // ---- convert + write next tile into the other buffer ----
        if (pre) {
            const int b = cur ^ 1;
            #pragma unroll
            for (int p = 0; p < 2; ++p) {
                int row = krow + 32 * p;
                bf16x8 s;
                s[0] = f2bf(kreg[2*p].x); s[1] = f2bf(kreg[2*p].y);
                s[2] = f2bf(kreg[2*p].z); s[3] = f2bf(kreg[2*p].w);
                s[4] = f2bf(kreg[2*p+1].x); s[5] = f2bf(kreg[2*p+1].y);
                s[6] = f2bf(kreg[2*p+1].z); s[7] = f2bf(kreg[2*p+1].w);
                *(bf16x8*)&Klds[b][row][SW(row, kc8)] = s;
            }
            bf16x8 a, bb;
            #pragma unroll
            for (int i = 0; i < 8; ++i) { a[i] = f2bf(vreg[i]); bb[i] = f2bf(vreg[8 + i]); }
            *(bf16x8*)&Vt[b][lane][SW(lane, wave * 16)]     = a;
            *(bf16x8*)&Vt[b][lane][SW(lane, wave * 16 + 8)] = bb;
        }
        __syncthreads();
    }

    // ---- epilogue: O / rowsum -> global (q = 4*lg+r, d = 16n+lr) ----
    float inv[4];
    #pragma unroll
    for (int r = 0; r < 4; ++r) inv[r] = 1.f / Dsum[r];
    float* orow = Og + base + (size_t)q0 * DH;
    #pragma unroll
    for (int r = 0; r < 4; ++r) {
        int q = 4 * lg + r;
        #pragma unroll
        for (int n = 0; n < 4; ++n)
            orow[(size_t)q * DH + 16 * n + lr] = Of[n][r] * inv[r];
    }
}

extern "C" void kernel_launch(void* const* d_in, const int* in_sizes, int n_in,
                              void* d_out, int out_size, void* d_ws, size_t ws_size,
                              hipStream_t stream) {
    const float* Q = (const float*)d_in[0];
    const float* K = (const float*)d_in[1];
    const float* V = (const float*)d_in[2];
    const int* lens = (const int*)d_in[3];
    float* O = (float*)d_out;
    dim3 grid(S_LEN / 64, 4 * 8);
    attn_fwd<<<grid, 256, 0, stream>>>(Q, K, V, lens, O);
}